// Round 12
// baseline (259.701 us; speedup 1.0000x reference)
//
#include <hip/hip_runtime.h>
#include <math.h>

#define BB 16
#define H 1024
#define W 1024
#define HW (H*W)
#define NTOT (BB*HW)
#define LISTCAP 65536

typedef unsigned long long u64;

// float32 of np.exp(-0.5*(n/1)^2), n=-2..2 (correctly-rounded decimal literals)
__device__ __constant__ float GW[5] = {
    0.13533528323661270f, 0.60653065971263342f, 1.0f,
    0.60653065971263342f, 0.13533528323661270f};

#define CSCALE ((float)(180.0 / 3.1415926))

// =====================================================================
// MEGA kernel: gaussian(h)+gaussian(v)+sobel+mag+bucket+NMS fused.
// Tile 128x8 output; mag computed on 130x10 (incl. NMS halo) in LDS.
// OUT-OF-IMAGE halo mag is ZERO (conv zero-pad semantics) — critical.
// sA: img rows y0-4..y0+11 (16) cols x0-4..x0+131 (136, stride 136)
// sB: gh   rows 16          cols x0-2..+129      (132, stride 132)
// sm overlays sA rows 0..11 <-> y0-2+rr, col c <-> x0-2+c (zero OOB)
// sM overlays sB rows 0..9  <-> y0-1+r,  col mc <-> x0-1+mc (zero if out-of-image)
// =====================================================================
__global__ __launch_bounds__(256, 8) void k_mega(const float* __restrict__ img,
                                                 float* __restrict__ mag,
                                                 u64* __restrict__ Mb,
                                                 float* __restrict__ partialA,
                                                 float* __restrict__ partialT,
                                                 unsigned int* __restrict__ list,
                                                 unsigned int* __restrict__ cnt) {
#pragma clang fp contract(off)
    __shared__ float sA[16 * 136 + 16];
    __shared__ float sB[16 * 132];
    __shared__ float red[256];
    __shared__ unsigned int nib32[256];

    const int tid = threadIdx.x;
    const int x0 = blockIdx.x * 128;
    const int y0 = blockIdx.y * 8;
    const int b = blockIdx.z;
    const size_t base = (size_t)b * HW;

    // ---- stage A: img tile + halo ----
    for (int idx = tid; idx < 16 * 34; idx += 256) {
        int r = idx / 34, v = idx - r * 34;
        int gy = y0 - 4 + r;
        int gxv = x0 - 4 + v * 4;
        float4 val = make_float4(0.f, 0.f, 0.f, 0.f);
        if (gy >= 0 && gy < H && gxv >= 0 && gxv <= W - 4)
            val = *(const float4*)&img[base + (size_t)gy * W + gxv];
        *(float4*)&sA[r * 136 + v * 4] = val;
    }
    __syncthreads();

    // ---- stage B: horizontal gaussian. gh col c <-> x0-2+c; taps sA c..c+4 ----
    for (int idx = tid; idx < 16 * 33; idx += 256) {
        int r = idx / 33, g = idx - r * 33;
        const float* p = &sA[r * 136 + g * 4];
        float4 A0 = *(const float4*)p;
        float4 A1 = *(const float4*)(p + 4);
        float a_[8] = {A0.x, A0.y, A0.z, A0.w, A1.x, A1.y, A1.z, A1.w};
        float o[4];
#pragma unroll
        for (int j = 0; j < 4; ++j) {
            float s = 0.0f;
#pragma unroll
            for (int k = 0; k < 5; ++k) s = s + GW[k] * a_[j + k];
            o[j] = s;
        }
        *(float4*)&sB[r * 132 + g * 4] = make_float4(o[0], o[1], o[2], o[3]);
    }
    __syncthreads();

    // ---- stage C: vertical gaussian -> sm (overlays sA), ZERO at image OOB ----
    for (int idx = tid; idx < 12 * 33; idx += 256) {
        int rr = idx / 33, g = idx - rr * 33;
        float bb[20];
#pragma unroll
        for (int k = 0; k < 5; ++k) {
            float4 t = *(const float4*)&sB[(rr + k) * 132 + g * 4];
            bb[k * 4 + 0] = t.x; bb[k * 4 + 1] = t.y;
            bb[k * 4 + 2] = t.z; bb[k * 4 + 3] = t.w;
        }
        int gy = y0 - 2 + rr;
        bool rowok = (gy >= 0 && gy < H);
        float o[4];
#pragma unroll
        for (int j = 0; j < 4; ++j) {
            float s = 0.0f;
#pragma unroll
            for (int k = 0; k < 5; ++k) s = s + GW[k] * bb[k * 4 + j];
            int gx = x0 - 2 + g * 4 + j;
            o[j] = (rowok && gx >= 0 && gx < W) ? s : 0.0f;
        }
        *(float4*)&sA[rr * 136 + g * 4] = make_float4(o[0], o[1], o[2], o[3]);
    }
    __syncthreads();

    // ---- stage D: mag for 10x130 tile -> sM (overlays sB) ----
    // mag(r,mc) <-> pixel (y0-1+r, x0-1+mc); OUT-OF-IMAGE -> 0 (conv zero-pad)
    float tmax = 0.0f;
    for (int idx = tid; idx < 330; idx += 256) {
        int r = idx / 33, g = idx - r * 33;
        int gy = y0 - 1 + r;
        bool rowok = (gy >= 0 && gy < H);
        const float* P0 = &sA[r * 136 + g * 4];
        const float* P1 = P0 + 136;
        const float* P2 = P1 + 136;
        float4 q0 = *(const float4*)P0; float2 e0 = *(const float2*)(P0 + 4);
        float4 q1 = *(const float4*)P1; float2 e1 = *(const float2*)(P1 + 4);
        float4 q2 = *(const float4*)P2; float2 e2 = *(const float2*)(P2 + 4);
        float r0[6] = {q0.x, q0.y, q0.z, q0.w, e0.x, e0.y};
        float r1[6] = {q1.x, q1.y, q1.z, q1.w, e1.x, e1.y};
        float r2[6] = {q2.x, q2.y, q2.z, q2.w, e2.x, e2.y};
        int nj = (g < 32) ? 4 : 2;   // mag cols 0..129 only
        float mg[4] = {0.f, 0.f, 0.f, 0.f};
#pragma unroll
        for (int j = 0; j < 4; ++j) {
            if (j >= nj) continue;
            float a00 = r0[j], a01 = r0[j + 1], a02 = r0[j + 2];
            float a10 = r1[j],                  a12 = r1[j + 2];
            float a20 = r2[j], a21 = r2[j + 1], a22 = r2[j + 2];
            float Ix = a00;
            Ix = Ix - a02;
            Ix = Ix + 2.0f * a10;
            Ix = Ix - 2.0f * a12;
            Ix = Ix + a20;
            Ix = Ix - a22;
            float Iy = a00;
            Iy = Iy + 2.0f * a01;
            Iy = Iy + a02;
            Iy = Iy - a20;
            Iy = Iy - 2.0f * a21;
            Iy = Iy - a22;
            float t1 = Ix * Ix;
            float t2 = Iy * Iy;
            float m = sqrtf(t1 + t2);
            int gx = x0 - 1 + g * 4 + j;
            bool ok = rowok && (gx >= 0) && (gx < W);
            m = ok ? m : 0.0f;           // zero-pad mag outside the image
            mg[j] = m;
            tmax = fmaxf(tmax, m);
        }
        if (g < 32) {
            *(float4*)&sB[r * 132 + g * 4] = make_float4(mg[0], mg[1], mg[2], mg[3]);
        } else {
            sB[r * 132 + 128] = mg[0];
            sB[r * 132 + 129] = mg[1];
        }
    }
    __syncthreads();

    // ---- stage E: bucket (recomputed sobel) + NMS for center 128x8 ----
    {
        const int r = tid >> 5;            // 0..7
        const int cg = (tid & 31) * 4;     // 0..124
        const int y = y0 + r;
        const float* P0 = &sA[(r + 1) * 136 + cg];
        const float* P1 = P0 + 136;
        const float* P2 = P1 + 136;
        float4 q0a = *(const float4*)P0, q0b = *(const float4*)(P0 + 4);
        float4 q1a = *(const float4*)P1, q1b = *(const float4*)(P1 + 4);
        float4 q2a = *(const float4*)P2, q2b = *(const float4*)(P2 + 4);
        float R0[8] = {q0a.x, q0a.y, q0a.z, q0a.w, q0b.x, q0b.y, q0b.z, q0b.w};
        float R1[8] = {q1a.x, q1a.y, q1a.z, q1a.w, q1b.x, q1b.y, q1b.z, q1b.w};
        float R2[8] = {q2a.x, q2a.y, q2a.z, q2a.w, q2b.x, q2b.y, q2b.z, q2b.w};

        float am[4];
        unsigned int nib = 0;
        float amax = 0.0f;
#pragma unroll
        for (int j = 0; j < 4; ++j) {
            float a00 = R0[j + 1], a01 = R0[j + 2], a02 = R0[j + 3];
            float a10 = R1[j + 1],                   a12 = R1[j + 3];
            float a20 = R2[j + 1], a21 = R2[j + 2], a22 = R2[j + 3];
            float Ix = a00;
            Ix = Ix - a02;
            Ix = Ix + 2.0f * a10;
            Ix = Ix - 2.0f * a12;
            Ix = Ix + a20;
            Ix = Ix - a22;
            float Iy = a00;
            Iy = Iy + 2.0f * a01;
            Iy = Iy + a02;
            Iy = Iy - a20;
            Iy = Iy - 2.0f * a21;
            Iy = Iy - a22;

            // octant -> NMS line (dy,dx); band -> exact double fallback
            float ax = fabsf(Ix), ay = fabsf(Iy);
            float mn = fminf(ax, ay), mx = fmaxf(ax, ay);
            float crb = mn * 0.92387953f - mx * 0.38268343f;
            int dy, dx;
            if (fabsf(crb) < mx * 3e-5f) {
                float fa2 = (float)atan2((double)Iy, (double)Ix);
                float d2 = fa2 * CSCALE;
                d2 = d2 + 180.0f;
                float t2d = d2 / 45.0f;
                float rr2 = rintf(t2d);
                int bidx = ((int)rr2) & 7;
                int t1 = (bidx + 1) & 7;
                dy = ((bidx >= 1 && bidx <= 3) ? 1 : 0) - ((bidx >= 5) ? 1 : 0);
                dx = ((t1 <= 2) ? 1 : 0) - ((t1 >= 4 && t1 <= 6) ? 1 : 0);
            } else if (ay <= ax * 0.41421356f) {
                dy = 0; dx = 1;                        // horizontal line
            } else if (ay >= ax * 2.41421356f) {
                dy = 1; dx = 0;                        // vertical line
            } else {
                bool sameq = (Iy >= 0.0f) == (Ix >= 0.0f);
                dy = 1; dx = sameq ? 1 : -1;           // diagonal line
            }

            const int mo = (r + 1) * 132 + cg + 1 + j;
            const int od = dy * 132 + dx;
            float a  = sB[mo];
            float bp = sB[mo + od];
            float bn = sB[mo - od];
            am[j] = a;

            bool g1 = a > bp, g2 = a > bn;
            bool f1 = a >= bp * 1.0000005f;
            bool f2 = a >= bn * 1.0000005f;
            bool im = g1 && g2;
            bool bad = (g1 && !f1) || (g2 && !f2);
            if (im && bad) {
                unsigned int pos = atomicAdd(cnt, 1u);
                if (pos < LISTCAP) {
                    int xcol = cg + j;
                    int widx = ((b << 8) | ((y >> 6) << 4) | ((x0 >> 6) + (xcol >> 6))) * 64 + (y & 63);
                    unsigned int meta = ((unsigned int)widx << 10) |
                                        ((unsigned int)(xcol & 63) << 4) | (unsigned int)b;
                    unsigned int* rec = list + (size_t)pos * 4;
                    rec[0] = __float_as_uint(a);
                    rec[1] = __float_as_uint(bp);
                    rec[2] = __float_as_uint(bn);
                    rec[3] = meta;
                }
            }
            if (im) {
                nib |= 1u << j;
                if (!bad) amax = fmaxf(amax, a);
            }
        }
        *(float4*)&mag[base + (size_t)y * W + x0 + cg] = make_float4(am[0], am[1], am[2], am[3]);
        nib32[tid] = nib;
        red[tid] = amax;
    }
    __syncthreads();

    // Mb assembly: 8 rows x 2 words
    if (tid < 16) {
        int rw = tid >> 1, h = tid & 1;
        u64 w = 0;
#pragma unroll
        for (int j = 0; j < 16; ++j)
            w |= (u64)nib32[rw * 32 + h * 16 + j] << (4 * j);
        int yy = y0 + rw;
        int widx = ((b << 8) | ((yy >> 6) << 4) | ((x0 >> 6) + h)) * 64 + (yy & 63);
        Mb[widx] = w;
    }

    // thin-raw (certain) block max
    for (int s = 128; s > 0; s >>= 1) {
        if (tid < s) red[tid] = fmaxf(red[tid], red[tid + s]);
        __syncthreads();
    }
    const int pb = (blockIdx.z * 128 + blockIdx.y) * 8 + blockIdx.x;
    if (tid == 0) partialT[pb] = red[0];
    __syncthreads();

    // mag block max (halo in-image values identical to owning tiles; OOB are 0)
    red[tid] = tmax;
    __syncthreads();
    for (int s = 128; s > 0; s >>= 1) {
        if (tid < s) red[tid] = fmaxf(red[tid], red[tid + s]);
        __syncthreads();
    }
    if (tid == 0) partialA[pb] = red[0];
}

// ---------------- per-image reductions: magmax + certain thin-raw max ----------------
__global__ __launch_bounds__(256) void k_redmax2(const float* __restrict__ pA,
                                                 const float* __restrict__ pT,
                                                 float* __restrict__ hdr,
                                                 float* __restrict__ thinraw) {
    __shared__ float red[256];
    const float* p = pA + blockIdx.x * 1024;
    float m = 0.0f;
    for (int k = threadIdx.x; k < 1024; k += 256) m = fmaxf(m, p[k]);
    red[threadIdx.x] = m;
    __syncthreads();
    for (int s = 128; s > 0; s >>= 1) {
        if (threadIdx.x < s) red[threadIdx.x] = fmaxf(red[threadIdx.x], red[threadIdx.x + s]);
        __syncthreads();
    }
    if (threadIdx.x == 0) hdr[blockIdx.x] = red[0];
    __syncthreads();
    const float* q = pT + blockIdx.x * 1024;
    m = 0.0f;
    for (int k = threadIdx.x; k < 1024; k += 256) m = fmaxf(m, q[k]);
    red[threadIdx.x] = m;
    __syncthreads();
    for (int s = 128; s > 0; s >>= 1) {
        if (threadIdx.x < s) red[threadIdx.x] = fmaxf(red[threadIdx.x], red[threadIdx.x + s]);
        __syncthreads();
    }
    if (threadIdx.x == 0) thinraw[blockIdx.x] = red[0];
}

// ---------------- fixup: resolve M-dependent NMS comparisons ----------------
__global__ void k_fixup(const float* __restrict__ hdr,
                        const unsigned int* __restrict__ list,
                        const unsigned int* __restrict__ cnt,
                        u64* __restrict__ Mb,
                        unsigned int* __restrict__ extraU) {
#pragma clang fp contract(off)
    unsigned int n = *cnt;
    if (n > LISTCAP) n = LISTCAP;
    for (unsigned int i = threadIdx.x; i < n; i += 256) {
        const unsigned int* rec = list + (size_t)i * 4;
        float a = __uint_as_float(rec[0]);
        float bp = __uint_as_float(rec[1]);
        float bn = __uint_as_float(rec[2]);
        unsigned int meta = rec[3];
        int b = meta & 15;
        int bit = (meta >> 4) & 63;
        int widx = meta >> 10;
        float M = hdr[b];
        bool g1 = a > bp, g2 = a > bn;
        bool f1 = a >= bp * 1.0000005f;
        bool f2 = a >= bn * 1.0000005f;
        bool r1 = g1, r2 = g2;
        float qa = a / M;
        if (g1 && !f1) r1 = qa > (bp / M);
        if (g2 && !f2) r2 = qa > (bn / M);
        if (r1 && r2) atomicMax(&extraU[b], __float_as_uint(a));
        else atomicAnd(&Mb[widx], ~(1ull << bit));
    }
}

// ---------------- global thin-max + per-image threshold bisection ----------------
__global__ void k_finalize2(const float* __restrict__ thinraw,
                            const unsigned int* __restrict__ extraU,
                            float* __restrict__ hdr,
                            float* __restrict__ thr) {
#pragma clang fp contract(off)
    __shared__ float timg[16];
    __shared__ float tms;
    int t = threadIdx.x;
    if (t < 16) {
        float M = hdr[t];
        float raw = fmaxf(thinraw[t], __uint_as_float(extraU[t]));
        timg[t] = raw / M;   // RN monotone: max-then-divide == divide-then-max
    }
    __syncthreads();
    if (t == 0) {
        float m = 0.0f;
        for (int i = 0; i < 16; ++i) m = fmaxf(m, timg[i]);
        hdr[16] = m;
        tms = m;
    }
    __syncthreads();
    if (t < 32) {
        float M = hdr[t >> 1];
        float T = (t & 1) ? (tms * 0.15f) : 0.00392f;
        if (0.0f / M >= T) { thr[t] = 0.0f; return; }
        unsigned int lo = 0u, hi = 0x7f800000u;
        while (hi - lo > 1u) {
            unsigned int mid = lo + ((hi - lo) >> 1);
            if (__uint_as_float(mid) / M >= T) hi = mid; else lo = mid;
        }
        thr[t] = __uint_as_float(hi);
    }
}

// ---------------- threshold: wave-mapped, ballots (unchanged) ----------------
__global__ __launch_bounds__(256, 8) void k_thresh_w(const float* __restrict__ mag,
                                                     const u64* __restrict__ Mb,
                                                     const float* __restrict__ hdr,
                                                     const float* __restrict__ thr,
                                                     u64* __restrict__ Sb,
                                                     u64* __restrict__ Wb) {
    const int tid = threadIdx.x;
    const int L = tid & 63, wv = tid >> 6;
    const int h = wv & 1, wr = wv >> 1;
    const int x0 = blockIdx.x * 128;
    const int y0 = blockIdx.y * 32;
    const int b = blockIdx.z;
    const size_t base = (size_t)b * HW;
    const float Alo = thr[b * 2], Ahi = thr[b * 2 + 1];
    const bool snm = (hdr[16] * 0.15f <= 0.0f);
    const int txw = (x0 >> 6) + h;

#pragma unroll 4
    for (int i = 0; i < 16; ++i) {
        const int r = i * 2 + wr;
        const int y = y0 + r;
        const int widx = ((b << 8) | ((y >> 6) << 4) | txw) * 64 + (y & 63);
        float a = mag[base + (size_t)y * W + x0 + h * 64 + L];
        u64 mw = Mb[widx];
        bool im = (mw >> L) & 1ull;
        bool strong = snm || (im && (a >= Ahi));
        bool weak = (!strong) && im && (a >= Alo);
        u64 sw = __ballot(strong);
        u64 ww = __ballot(weak);
        if (L == 0) { Sb[widx] = sw; Wb[widx] = ww; }
    }
}

// ---------------- hysteresis: bit-parallel 64x64 tile per wave (unchanged) ----------------
template <bool LAST>
__global__ __launch_bounds__(256) void k_hyster_bits(const u64* __restrict__ Wb,
                                                     u64* __restrict__ Sb,
                                                     float* __restrict__ out) {
    const int lane = threadIdx.x & 63;
    const int t = blockIdx.x * 4 + (threadIdx.x >> 6);
    const int ty = (t >> 4) & 15;
    const int tx = t & 15;
    const int idx = t * 64 + lane;

    u64 S = Sb[idx];
    const u64 Wk = Wb[idx];

    u64 hstat = 0;
    if (tx > 0)  hstat |= (Sb[(t - 1) * 64 + lane] >> 63) & 1ull;
    if (tx < 15) hstat |= (Sb[(t + 1) * 64 + lane] & 1ull) << 63;

    u64 halo = 0;
    if (lane == 0 && ty > 0) {
        const int ta = t - 16;
        u64 tc = Sb[ta * 64 + 63];
        u64 hh = (tc << 1) | tc | (tc >> 1);
        if (tx > 0)  hh |= (Sb[(ta - 1) * 64 + 63] >> 63) & 1ull;
        if (tx < 15) hh |= (Sb[(ta + 1) * 64 + 63] & 1ull) << 63;
        halo = hh;
    }
    if (lane == 63 && ty < 15) {
        const int tb = t + 16;
        u64 tc = Sb[tb * 64 + 0];
        u64 hh = (tc << 1) | tc | (tc >> 1);
        if (tx > 0)  hh |= (Sb[(tb - 1) * 64 + 0] >> 63) & 1ull;
        if (tx < 15) hh |= (Sb[(tb + 1) * 64 + 0] & 1ull) << 63;
        halo = hh;
    }

    for (int it = 0; it < 160; ++it) {
        u64 hh = (S << 1) | S | (S >> 1) | hstat;
        u64 up = __shfl_up(hh, 1, 64);
        if (lane == 0) up = halo;
        u64 dn = __shfl_down(hh, 1, 64);
        if (lane == 63) dn = halo;
        u64 dil = hh | up | dn;
        u64 nS = S | (Wk & dil);
        bool ch = (nS != S);
        S = nS;
        if (!__any(ch)) break;
    }

    if (!LAST) {
        Sb[idx] = S;
    } else {
        const int bimg = t >> 8;
        float* op = out + (size_t)bimg * HW + (size_t)(ty * 64) * W + tx * 64 + lane;
#pragma unroll 4
        for (int rr = 0; rr < 64; ++rr) {
            u64 wrow = __shfl(S, rr, 64);
            op[(size_t)rr * W] = ((wrow >> lane) & 1ull) ? 255.0f : 0.0f;
        }
    }
}

extern "C" void kernel_launch(void* const* d_in, const int* in_sizes, int n_in,
                              void* d_out, int out_size, void* d_ws, size_t ws_size,
                              hipStream_t stream) {
    (void)in_sizes; (void)n_in; (void)out_size; (void)ws_size;
    const float* img = (const float*)d_in[0];
    float* out = (float*)d_out;

    // workspace layout (floats unless noted)
    float* hdr = (float*)d_ws;                    // [0..15] magmax, [16] thinmax,
                                                  // [32..47] extraU (uint), [48] cnt (uint)
    unsigned int* extraU = (unsigned int*)(hdr + 32);
    unsigned int* cnt = (unsigned int*)(hdr + 48);
    float* thr = hdr + 64;                        // [64..95] per-image Alo/Ahi
    float* thinraw = hdr + 96;                    // [96..111]
    float* partialA = hdr + 128;                  // 16384
    float* partialT = partialA + 16384;           // 16384
    unsigned int* list = (unsigned int*)(partialT + 16384);  // 64K x 4 uints = 1 MB
    float* A = (float*)(list + (size_t)LISTCAP * 4);         // mag, 64 MB
    u64* Sb = (u64*)(A + (size_t)NTOT);           // strong bits, 2 MB
    u64* Wb = Sb + NTOT / 64;                     // weak bits, 2 MB
    u64* Mb = Wb + NTOT / 64;                     // is_max bits, 2 MB

    hipMemsetAsync(d_ws, 0, 256, stream);         // zeroes extraU + cnt

    dim3 blk(256);
    k_mega<<<dim3(8, 128, BB), blk, 0, stream>>>(img, A, Mb, partialA, partialT, list, cnt);
    k_redmax2<<<dim3(BB), blk, 0, stream>>>(partialA, partialT, hdr, thinraw);
    k_fixup<<<dim3(1), blk, 0, stream>>>(hdr, list, cnt, Mb, extraU);
    k_finalize2<<<dim3(1), dim3(64), 0, stream>>>(thinraw, extraU, hdr, thr);
    k_thresh_w<<<dim3(8, 32, BB), blk, 0, stream>>>(A, Mb, hdr, thr, Sb, Wb);
    for (int p = 0; p < 5; ++p)
        k_hyster_bits<false><<<dim3(NTOT / (64 * 64) / 4), blk, 0, stream>>>(Wb, Sb, out);
    k_hyster_bits<true><<<dim3(NTOT / (64 * 64) / 4), blk, 0, stream>>>(Wb, Sb, out);
}